// Round 2
// baseline (235.579 us; speedup 1.0000x reference)
//
#include <hip/hip_runtime.h>

// out[b, c] = x[b, c] * diag[c]   for x:(8192, 4096) fp32, diag:(4096,) fp32.
// Memory-bound streaming kernel. Ideal traffic = 268.4 MB -> ~43 us at 6.3 TB/s.
//
// Structure:
//  - Grid capped at 4096 blocks (G11), grid-stride with 8 float4 per thread,
//    fully unrolled -> 8 independent outstanding load/store pairs per thread.
//  - STRIDE (4096*256 = 1,048,576 float4) is a multiple of SIZE4 (1024), so a
//    thread's column index is the SAME for all 8 iterations -> diag loaded
//    ONCE per thread into registers, reused 8x.
//  - Nontemporal load/store on the streaming x/out (touched exactly once):
//    keeps them from churning L2, skips write-allocate on stores.
//  - NOTE: __builtin_nontemporal_* requires a native clang vector type, not
//    HIP_vector_type (struct) -> use ext_vector_type(4) float alias.

typedef float f32x4 __attribute__((ext_vector_type(4)));

#define SIZE4 1024                  // 4096 / 4 columns in float4 units
#define N4 8388608                  // 8192 * 4096 / 4 total float4
#define TPB 256
#define BLOCKS 4096
#define PER_THREAD 8                // N4 / (BLOCKS * TPB)
#define STRIDE (BLOCKS * TPB)       // 1,048,576; % SIZE4 == 0 -> column invariant

__global__ __launch_bounds__(TPB) void diag_scale_kernel(
    const f32x4* __restrict__ x,
    const f32x4* __restrict__ d,
    f32x4* __restrict__ out)
{
    const int tid = blockIdx.x * TPB + threadIdx.x;       // 0 .. STRIDE-1
    const f32x4 dv = d[tid & (SIZE4 - 1)];                // column fixed for all k

    #pragma unroll
    for (int k = 0; k < PER_THREAD; ++k) {
        const int i = tid + k * STRIDE;                   // exact cover of N4
        const f32x4 xv = __builtin_nontemporal_load(&x[i]);
        const f32x4 r = xv * dv;                          // elementwise vector mul
        __builtin_nontemporal_store(r, &out[i]);
    }
}

extern "C" void kernel_launch(void* const* d_in, const int* in_sizes, int n_in,
                              void* d_out, int out_size, void* d_ws, size_t ws_size,
                              hipStream_t stream)
{
    const f32x4* x = (const f32x4*)d_in[0];   // (8192, 4096) fp32
    const f32x4* d = (const f32x4*)d_in[1];   // (4096,) fp32
    f32x4* out = (f32x4*)d_out;               // (8192, 4096) fp32

    diag_scale_kernel<<<BLOCKS, TPB, 0, stream>>>(x, d, out);
}